// Round 8
// baseline (449.976 us; speedup 1.0000x reference)
//
#include <hip/hip_runtime.h>

typedef unsigned short u16;
typedef unsigned int u32;
typedef _Float16 h16;
typedef __attribute__((ext_vector_type(2))) _Float16 half2v;
typedef __attribute__((ext_vector_type(8))) _Float16 half8;
typedef __attribute__((ext_vector_type(8))) unsigned short ushort8;
typedef __attribute__((ext_vector_type(4))) float f32x4;
typedef __attribute__((ext_vector_type(16))) float f32x16;

#define NPAIRS 15625            // 500000 / 32: each block = 4 waves = 2 strips (M=32)

// Planar hi/lo layout: value (row r in [0,16), col c) of buffer with stride S:
//   hi at base + r*S + c, lo at base + (16+r)*S + c. Strip 1 at +STRIP.
// SPILL=1 arena (38912 B -> 4 blocks/CU): E1 @0, CT @1280; E2 lives in global ews.
// SPILL=0 arena (48128 B -> 3 blocks/CU): E1 @0, E2 @1280, CT @3584 (r7 layout).
#define SE1 40
#define SE2 72
#define SCT 264
#define SMR 264                 // MR aliases CT cols [128:256)

// 32x32x16 f16 MFMA: A row = lane&31, k = (lane>>5)*8+j; B col = lane&31, same k;
// C/D: col = lane&31, row = (reg&3) + 8*(reg>>2) + 4*(lane>>5)  [HW-verified map]
#define MFMA32(A,B,C) __builtin_amdgcn_mfma_f32_32x32x16_f16(A,B,C,0,0,0)

// light barrier: drain LDS ops only; global (B-prefetch) loads stay in flight
#define LBAR() asm volatile("s_waitcnt lgkmcnt(0)\n\ts_barrier" ::: "memory")
// full barrier: also drain global stores (E2 spill producer -> consumer via L2)
#define FBAR() asm volatile("s_waitcnt vmcnt(0) lgkmcnt(0)\n\ts_barrier" ::: "memory")
#define LWAIT() asm volatile("s_waitcnt lgkmcnt(0)" ::: "memory")

// ---------------- packed weight frag-pairs (f16 hi/lo, 32-wide tiles) ----------------
// fragpair f = FO[layer] + ct32*KS + ks, lane l, 32 B:
//   wp[(f*64+l)*16 + j]   = hi = f16(W[k][col])   (j=0..7)
//   wp[(f*64+l)*16 + 8+j] = lo = f16(W - (float)hi)
// col = ct32*32 + (l&31), k = ks*16 + (l>>5)*8 + j; zero-pad k >= K_actual.
#define F_L0   0
#define F_L1   1
#define F_L2   3
#define F_L3   7
#define F_L4   23
#define F_L5   55
#define F_L6   119
#define F_L7   135
#define F_L8   143
#define F_L9   159
#define F_L10  163
#define F_L11  165
#define F_L12  169
#define NFRAG  171              // packed bytes: 171*1024*2 = 350208
#define EWS_OFF 350208          // E2 spill region starts here in d_ws
#define EWS_BLK 4096            // h16 per block: [ks:4][plane:2][row:32][c:16] = 8192 B

__device__ __forceinline__ u16 hb(h16 h) { union { h16 h; u16 u; } v; v.h = h; return v.u; }

__global__ __launch_bounds__(256) void pack_w(
    const float* w0, const float* w1, const float* w2, const float* w3, const float* w4,
    const float* w5, const float* w6, const float* w7, const float* w8, const float* w9,
    const float* w10, const float* w11, const float* w12, u16* __restrict__ packed)
{
  const float* ws[13] = {w0,w1,w2,w3,w4,w5,w6,w7,w8,w9,w10,w11,w12};
  const int Ka[13]  = {16,32,32,64,128,256,128,64,128,64,32,64,32};
  const int KS[13]  = {1,2,2,4,8,16,8,4,8,4,2,4,2};
  const int CO[13]  = {32,32,64,128,128,128,64,64,64,32,32,32,32};
  const int FO[13]  = {F_L0,F_L1,F_L2,F_L3,F_L4,F_L5,F_L6,F_L7,F_L8,F_L9,F_L10,F_L11,F_L12};
  int g = blockIdx.x * 256 + threadIdx.x;
  int f = g >> 6, lane = g & 63;
  if (f >= NFRAG) return;
  int layer = 0;
#pragma unroll
  for (int i = 1; i < 13; ++i) if (f >= FO[i]) layer = i;
  int fl = f - FO[layer];
  int ks = fl % KS[layer];
  int ct = fl / KS[layer];
  int cout = CO[layer];
  int col  = ct * 32 + (lane & 31);
  u16 thi[8], tlo[8];
#pragma unroll
  for (int j = 0; j < 8; ++j) {
    int k = ks * 16 + (lane >> 5) * 8 + j;
    float w = (k < Ka[layer]) ? ws[layer][k * cout + col] : 0.f;
    h16 h = (h16)w;
    h16 l = (h16)(w - (float)h);
    thi[j] = hb(h); tlo[j] = hb(l);
  }
  u16* dst = packed + ((size_t)f * 64 + lane) * 16;
  *(ushort8*)dst       = *(const ushort8*)thi;
  *(ushort8*)(dst + 8) = *(const ushort8*)tlo;
}

// ---------------- fused backbone ----------------

struct fragp { half8 h, l; };

#define LOADFP(DST, BIDX)                                                       \
  do { const h16* _fp = wp + (((size_t)(BIDX)) * 64 + lane) * 16;               \
       (DST).h = *(const half8*)_fp; (DST).l = *(const half8*)(_fp + 8); } while (0)

// prefetch first min(KS,4) fragpairs of tile (FOFF,CIDX) into pf0..pf3 (pre-barrier)
#define PFC(FOFF, CIDX, KS_)                                                    \
  do { const int _fb = (FOFF) + (CIDX) * (KS_);                                 \
       LOADFP(pf0, _fb);                                                        \
       if ((KS_) > 1) LOADFP(pf1, _fb + 1);                                     \
       if ((KS_) > 2) LOADFP(pf2, _fb + 2);                                     \
       if ((KS_) > 3) LOADFP(pf3, _fb + 3); } while (0)

// one K-step: 3 MFMAs split across two accumulator chains
#define KSTEP(BP, KSI)                                                          \
  do { const h16* _p = asrc + abase + (KSI) * 16;                               \
       half8 _ah = *(const half8*)_p;                                           \
       half8 _al = *(const half8*)(_p + alo);                                   \
       accB = MFMA32(_al, (BP).h, accB);                                        \
       accA = MFMA32(_ah, (BP).h, accA);                                        \
       accB = MFMA32(_ah, (BP).l, accB); } while (0)

__device__ __forceinline__ void splitw(h16* dst, int idx, int dlo, float v) {
  h16 h = (h16)v;
  dst[idx]       = h;
  dst[idx + dlo] = (h16)(v - (float)h);
}

__device__ __forceinline__ float red2p(const h16* catS, int cs, int r16, int cc) {
  half2v hp = *reinterpret_cast<const half2v*>(catS + r16 * cs + 2 * cc);
  half2v lp = *reinterpret_cast<const half2v*>(catS + (r16 + 16) * cs + 2 * cc);
  return (float)hp.x + (float)hp.y + (float)lp.x + (float)lp.y;
}

// One 32x32 output tile (rows = strip pair, cols = ct*32..+31), K = KS_*16.
// B fragpairs software-pipelined in 4-wide register chunks.
// EPI 0: relu->LDS | 1: +pair-red(cat) | 2: ->global fp32 | 3: ->global E2 spill
// BAR=1: block barrier between all LDS reads and epilogue writes (S5 aliasing).
template<int KS_, int EPI, int BAR>
__device__ __forceinline__ void layer32(
    const h16* __restrict__ asrc, int as, int strip,
    const h16* __restrict__ wp, int foff, int ct, int lane,
    fragp pf0, fragp pf1, fragp pf2, fragp pf3,
    h16* dst, int ds, int colb, const h16* cat, int cs,
    float* __restrict__ gout, int row0)
{
  const int ra = lane & 31;
  const int abase = (ra >> 4) * strip + (ra & 15) * as + ((lane >> 5) << 3);
  const int alo = 16 * as;
  const int fb = foff + ct * KS_;
  f32x16 accA = {0.f,0.f,0.f,0.f,0.f,0.f,0.f,0.f,0.f,0.f,0.f,0.f,0.f,0.f,0.f,0.f};
  f32x16 accB = {0.f,0.f,0.f,0.f,0.f,0.f,0.f,0.f,0.f,0.f,0.f,0.f,0.f,0.f,0.f,0.f};
  fragp cur0 = pf0, cur1 = pf1, cur2 = pf2, cur3 = pf3;
  constexpr int NCH = (KS_ + 3) / 4;
#pragma unroll
  for (int ch = 0; ch < NCH; ++ch) {
    fragp nx0, nx1, nx2, nx3;
    if (ch + 1 < NCH) {           // issue next chunk's B loads before this chunk's MFMAs
      const int nb = fb + (ch + 1) * 4;
      LOADFP(nx0, nb + 0); LOADFP(nx1, nb + 1);
      LOADFP(nx2, nb + 2); LOADFP(nx3, nb + 3);
    }
    const int k0 = ch * 4;
    if (k0 + 0 < KS_) KSTEP(cur0, k0 + 0);
    if (k0 + 1 < KS_) KSTEP(cur1, k0 + 1);
    if (k0 + 2 < KS_) KSTEP(cur2, k0 + 2);
    if (k0 + 3 < KS_) KSTEP(cur3, k0 + 3);
    if (ch + 1 < NCH) { cur0 = nx0; cur1 = nx1; cur2 = nx2; cur3 = nx3; }
  }
  const int cc  = ct * 32 + (lane & 31);
  const int hl4 = (lane >> 5) << 2;
  float vr[16];
#pragma unroll
  for (int i = 0; i < 16; ++i) {
    const int rr = (i & 3) + ((i >> 2) << 3) + hl4;
    float v = accA[i] + accB[i];
    v = v > 0.f ? v : 0.f;
    if (EPI == 1)
      v += red2p(cat + (rr >> 4) * strip, cs, rr & 15, cc);
    vr[i] = v;
  }
  if (BAR) LBAR();                 // all reads of aliased region done before any write
  if constexpr (EPI <= 1) {
    const int dlo = 16 * ds;
#pragma unroll
    for (int i = 0; i < 16; ++i) {
      const int rr = (i & 3) + ((i >> 2) << 3) + hl4;
      splitw(dst + (rr >> 4) * strip, (rr & 15) * ds + colb + cc, dlo, vr[i]);
    }
  } else if constexpr (EPI == 2) {
#pragma unroll
    for (int i = 0; i < 16; ++i) {
      const int rr = (i & 3) + ((i >> 2) << 3) + hl4;
      gout[(size_t)(row0 + rr) * 32 + cc] = vr[i];
    }
  } else {                         // EPI==3: E2 spill [ks][plane][row][16] (dst = global)
#pragma unroll
    for (int i = 0; i < 16; ++i) {
      const int rr = (i & 3) + ((i >> 2) << 3) + hl4;
      const int sa = ((cc >> 4) << 10) + rr * 16 + (cc & 15);
      h16 h = (h16)vr[i];
      dst[sa]       = h;
      dst[sa + 512] = (h16)(vr[i] - (float)h);
    }
  }
}

// 32x32 tile with A read from the global E2 spill (KS_<=4; all B pre-fetched).
template<int KS_>
__device__ __forceinline__ void layer32g(
    const h16* __restrict__ esp, const h16* __restrict__ wp, int foff, int ct, int lane,
    fragp pf0, fragp pf1, fragp pf2, fragp pf3,
    h16* dst, int ds, int colb, int strip)
{
  static_assert(KS_ <= 4, "layer32g handles one B chunk");
  const int ab = (lane & 31) * 16 + ((lane >> 5) << 3);
  half8 ah[KS_], al[KS_];
#pragma unroll
  for (int ks = 0; ks < KS_; ++ks) {
    ah[ks] = *(const half8*)(esp + ks * 1024 + ab);
    al[ks] = *(const half8*)(esp + ks * 1024 + 512 + ab);
  }
  f32x16 accA = {0.f,0.f,0.f,0.f,0.f,0.f,0.f,0.f,0.f,0.f,0.f,0.f,0.f,0.f,0.f,0.f};
  f32x16 accB = {0.f,0.f,0.f,0.f,0.f,0.f,0.f,0.f,0.f,0.f,0.f,0.f,0.f,0.f,0.f,0.f};
  if (KS_ > 0) { accB = MFMA32(al[0], pf0.h, accB); accA = MFMA32(ah[0], pf0.h, accA); accB = MFMA32(ah[0], pf0.l, accB); }
  if (KS_ > 1) { accB = MFMA32(al[1], pf1.h, accB); accA = MFMA32(ah[1], pf1.h, accA); accB = MFMA32(ah[1], pf1.l, accB); }
  if (KS_ > 2) { accB = MFMA32(al[2], pf2.h, accB); accA = MFMA32(ah[2], pf2.h, accA); accB = MFMA32(ah[2], pf2.l, accB); }
  if (KS_ > 3) { accB = MFMA32(al[3], pf3.h, accB); accA = MFMA32(ah[3], pf3.h, accA); accB = MFMA32(ah[3], pf3.l, accB); }
  const int cc  = ct * 32 + (lane & 31);
  const int hl4 = (lane >> 5) << 2;
  const int dlo = 16 * ds;
#pragma unroll
  for (int i = 0; i < 16; ++i) {
    const int rr = (i & 3) + ((i >> 2) << 3) + hl4;
    float v = accA[i] + accB[i];
    v = v > 0.f ? v : 0.f;
    splitw(dst + (rr >> 4) * strip, (rr & 15) * ds + colb + cc, dlo, v);
  }
}

template<int SPILL>
__global__ __launch_bounds__(256, 4) void backbone(
    const float* __restrict__ feat, const h16* __restrict__ wp,
    h16* __restrict__ ews, float* __restrict__ out)
{
  constexpr int STRIP = SPILL ? 9728 : 12032;      // 38912 B vs 48128 B total
  constexpr int ACTo  = SPILL ? 1280 : 3584;
  __shared__ h16 lds[2 * STRIP];
  const int lane = threadIdx.x & 63;
  const int wv   = threadIdx.x >> 6;     // 0..3
  const int row0 = blockIdx.x * 32;

  h16* E1 = lds;                          // 32 cols @0
  h16* E2 = SPILL ? nullptr : (lds + 1280);
  h16* CT = lds + ACTo;                   // 256 cols
  h16* MR = CT + 128;                     // aliases CT cols [128:256)
  h16* esp = SPILL ? (ews + (size_t)blockIdx.x * EWS_BLK) : nullptr;

  fragp pf0{}, pf1{}, pf2{}, pf3{};

  // ---- P0 (w0 only): S0: feat (K=16, exact) -> CT[:,0:32]; then S1: CT -> E1
  if (wv == 0) {
    PFC(F_L0, 0, 1);
    const int ra = lane & 31;
    const float* sp = feat + (size_t)(row0 + ra) * 16 + ((lane >> 5) << 3);
    f32x4 ua = *(const f32x4*)sp, ub = *(const f32x4*)(sp + 4);
    h16 th[8], tl[8];
#pragma unroll
    for (int j = 0; j < 4; ++j) {
      h16 h;
      h = (h16)ua[j]; th[j]   = h; tl[j]   = (h16)(ua[j] - (float)h);
      h = (h16)ub[j]; th[4+j] = h; tl[4+j] = (h16)(ub[j] - (float)h);
    }
    half8 ah = *(const half8*)th, al = *(const half8*)tl;
    f32x16 a = {0.f,0.f,0.f,0.f,0.f,0.f,0.f,0.f,0.f,0.f,0.f,0.f,0.f,0.f,0.f,0.f};
    a = MFMA32(al, pf0.h, a); a = MFMA32(ah, pf0.l, a); a = MFMA32(ah, pf0.h, a);
    const int cl = lane & 31, hl4 = (lane >> 5) << 2;
    const int dlo = 16 * SCT;
#pragma unroll
    for (int i = 0; i < 16; ++i) {
      const int rr = (i & 3) + ((i >> 2) << 3) + hl4;
      splitw(CT + (rr >> 4) * STRIP, (rr & 15) * SCT + cl, dlo, a[i] > 0.f ? a[i] : 0.f);
    }
    PFC(F_L1, 0, 2);
    LWAIT();                       // own writes drained before same-wave read
    layer32<2,0,0>(CT, SCT, STRIP, wp, F_L1, 0, lane, pf0,pf1,pf2,pf3,
                   E1, SE1, 0, nullptr, 0, nullptr, 0);
    PFC(F_L2, 0, 2);
  } else if (wv == 1) {
    PFC(F_L2, 1, 2);
  }
  LBAR();  // B1

  // ---- P1 (w0,w1): S2: e1(E1) -> E2  (LDS, or global spill when SPILL)
  if (wv < 2) {
    if constexpr (SPILL) {
      layer32<2,3,0>(E1, SE1, STRIP, wp, F_L2, wv, lane, pf0,pf1,pf2,pf3,
                     esp, 0, 0, nullptr, 0, nullptr, 0);
    } else {
      layer32<2,0,0>(E1, SE1, STRIP, wp, F_L2, wv, lane, pf0,pf1,pf2,pf3,
                     E2, SE2, 0, nullptr, 0, nullptr, 0);
    }
  }
  PFC(F_L3, wv, 4);
  if constexpr (SPILL) FBAR(); else LBAR();   // B2 (drain E2 spill stores to L2)

  // ---- P2 (all 4): S3: e2 -> CT[:,0:128]
  if constexpr (SPILL) {
    layer32g<4>(esp, wp, F_L3, wv, lane, pf0,pf1,pf2,pf3, CT, SCT, 0, STRIP);
  } else {
    layer32<4,0,0>(E2, SE2, STRIP, wp, F_L3, wv, lane, pf0,pf1,pf2,pf3,
                   CT, SCT, 0, nullptr, 0, nullptr, 0);
  }
  PFC(F_L4, wv, 8);
  LBAR();  // B3

  // ---- P3 (all 4): S4: e3(CT[0:128]) -> CT[:,128:256]  (write region disjoint)
  layer32<8,0,0>(CT, SCT, STRIP, wp, F_L4, wv, lane, pf0,pf1,pf2,pf3,
                 CT, SCT, 128, nullptr, 0, nullptr, 0);
  PFC(F_L5, wv, 16);
  LBAR();  // B4

  // ---- P4 (all 4): S5: merge3(CT[0:256]) + red -> MR[:,0:128]  (MR aliases
  //      CT[128:256): mid-stage barrier inside layer32 orders reads before writes)
  layer32<16,1,1>(CT, SCT, STRIP, wp, F_L5, wv, lane, pf0,pf1,pf2,pf3,
                  MR, SMR, 0, CT, SCT, nullptr, 0);
  if (wv < 2) PFC(F_L6, wv, 8); else PFC(F_L7, wv - 2, 4);
  LBAR();  // B5

  // ---- P5: w0,w1: L6: x2(MR[0:128]) -> CT[:,0:64]
  //          w2,w3: L7: lat2(e2)      -> CT[:,64:128]     (all regions disjoint)
  if (wv < 2) {
    layer32<8,0,0>(MR, SMR, STRIP, wp, F_L6, wv, lane, pf0,pf1,pf2,pf3,
                   CT, SCT, 0, nullptr, 0, nullptr, 0);
    PFC(F_L8, wv, 8);
  } else {
    if constexpr (SPILL) {
      layer32g<4>(esp, wp, F_L7, wv - 2, lane, pf0,pf1,pf2,pf3, CT, SCT, 64, STRIP);
    } else {
      layer32<4,0,0>(E2, SE2, STRIP, wp, F_L7, wv - 2, lane, pf0,pf1,pf2,pf3,
                     CT, SCT, 64, nullptr, 0, nullptr, 0);
    }
  }
  LBAR();  // B6

  // ---- P6 (w0,w1): L8: merge2(CT[0:128]) + red -> MR[:,0:64]
  //      (writes phys CT[128:192): disjoint from this stage's reads)
  if (wv < 2) {
    layer32<8,1,0>(CT, SCT, STRIP, wp, F_L8, wv, lane, pf0,pf1,pf2,pf3,
                   MR, SMR, 0, CT, SCT, nullptr, 0);
  }
  if (wv == 0) PFC(F_L9, 0, 4);
  else if (wv == 1) PFC(F_L10, 0, 2);
  LBAR();  // B7

  // ---- P7: w0: L9: x1(MR[0:64]) -> CT[:,0:32];  w1: L10: lat1(E1) -> CT[:,32:64]
  if (wv == 0) {
    layer32<4,0,0>(MR, SMR, STRIP, wp, F_L9, 0, lane, pf0,pf1,pf2,pf3,
                   CT, SCT, 0, nullptr, 0, nullptr, 0);
    PFC(F_L11, 0, 4);
  } else if (wv == 1) {
    layer32<2,0,0>(E1, SE1, STRIP, wp, F_L10, 0, lane, pf0,pf1,pf2,pf3,
                   CT, SCT, 32, nullptr, 0, nullptr, 0);
  }
  LBAR();  // B8

  // ---- P8 (w0 only): L11: merge1(CT[0:64]) + red -> MR[:,0:32]  (disjoint);
  //      then L12: out(MR[0:32]) -> global fp32 [N,32]  (same-wave RAW: lgkm wait)
  if (wv == 0) {
    layer32<4,1,0>(CT, SCT, STRIP, wp, F_L11, 0, lane, pf0,pf1,pf2,pf3,
                   MR, SMR, 0, CT, SCT, nullptr, 0);
    PFC(F_L12, 0, 2);
    LWAIT();
    layer32<2,2,0>(MR, SMR, STRIP, wp, F_L12, 0, lane, pf0,pf1,pf2,pf3,
                   nullptr, 0, 0, nullptr, 0, out, row0);
  }
}

extern "C" void kernel_launch(void* const* d_in, const int* in_sizes, int n_in,
                              void* d_out, int out_size, void* d_ws, size_t ws_size,
                              hipStream_t stream) {
  (void)in_sizes; (void)n_in; (void)out_size;
  u16* packed = (u16*)d_ws;   // 350208 B
  h16* ews = (h16*)((char*)d_ws + EWS_OFF);
  const bool spill = ws_size >= (size_t)EWS_OFF + (size_t)NPAIRS * EWS_BLK * 2;

  // order: in, enc1, enc2, enc3, lat3, merge3, up3, lat2, merge2, up2, lat1, merge1, up1
  hipLaunchKernelGGL(pack_w, dim3(43), dim3(256), 0, stream,
      (const float*)d_in[2],  (const float*)d_in[3],  (const float*)d_in[4],
      (const float*)d_in[5],  (const float*)d_in[8],  (const float*)d_in[11],
      (const float*)d_in[14], (const float*)d_in[7],  (const float*)d_in[10],
      (const float*)d_in[13], (const float*)d_in[6],  (const float*)d_in[9],
      (const float*)d_in[12], packed);

  if (spill) {
    hipLaunchKernelGGL((backbone<1>), dim3(NPAIRS), dim3(256), 0, stream,
                       (const float*)d_in[0], (const h16*)packed, ews, (float*)d_out);
  } else {
    hipLaunchKernelGGL((backbone<0>), dim3(NPAIRS), dim3(256), 0, stream,
                       (const float*)d_in[0], (const h16*)packed, (h16*)nullptr, (float*)d_out);
  }
}